// Round 1
// baseline (1059.100 us; speedup 1.0000x reference)
//
#include <hip/hip_runtime.h>
#include <math.h>

#define BB 4
#define HW 4096
#define CC 256
#define FC 64

#define TI 32
#define TJ 64
#define SPLIT 4
#define EPAD 68   // 64 + 4 pad -> odd 16B-granule stride for conflict-free b128
#define SPAD 36   // s-tile row pad (16B aligned)

#define TI2 8     // rows per block in shortcut kernel

// ws layout (float offsets)
#define OFF_EMB 0
#define OFF_SC   (BB*HW*FC)            // 1,048,576
#define OFF_SQN  (OFF_SC + BB*HW*CC)   // 5,242,880
#define OFF_T    (OFF_SQN + BB*HW)
#define OFF_D    (OFF_T + BB*HW)

// ---------------------------------------------------------------------------
// K1: emb[r,f] = fm[r,:] . W_emb[f,:] + b_emb[f];  sqn[r] = |emb[r,:]|^2
//     also zeroes D[r] for K3's atomics.
// grid: B*HW blocks of 64 threads (thread = f)
// ---------------------------------------------------------------------------
__global__ __launch_bounds__(64) void k_emb(const float* __restrict__ fm,
    const float* __restrict__ Wemb, const float* __restrict__ bemb,
    float* __restrict__ emb, float* __restrict__ sqn, float* __restrict__ D)
{
    const int r = blockIdx.x;
    const int t = threadIdx.x;
    __shared__ float row[CC];
    ((float4*)row)[t] = ((const float4*)(fm + (size_t)r * CC))[t];
    __syncthreads();
    const float4* w4 = (const float4*)(Wemb + (size_t)t * CC);
    float s = 0.f;
    #pragma unroll 8
    for (int k4 = 0; k4 < CC/4; ++k4) {
        float4 w = w4[k4];
        float4 x = ((const float4*)row)[k4];
        s += x.x*w.x + x.y*w.y + x.z*w.z + x.w*w.w;
    }
    s += bemb[t];
    emb[(size_t)r * FC + t] = s;
    float q = s * s;
    #pragma unroll
    for (int off = 32; off; off >>= 1) q += __shfl_down(q, off);
    if (t == 0) { sqn[r] = q; D[r] = 0.f; }
}

// ---------------------------------------------------------------------------
// K2: sc[r,d] = fm[r,:] . W_att[d,:] + b_att[d];  T[r] = sc[r,:].W_thr + b_thr
// grid: B*HW/TI2 blocks of 256 threads (thread = d), TI2 rows per block
// ---------------------------------------------------------------------------
__global__ __launch_bounds__(256) void k_sc(const float* __restrict__ fm,
    const float* __restrict__ Watt, const float* __restrict__ batt,
    const float* __restrict__ Wthr, const float* __restrict__ bthr,
    float* __restrict__ sc, float* __restrict__ T)
{
    const int r0 = blockIdx.x * TI2;
    const int t = threadIdx.x;
    __shared__ float rows[TI2][CC];
    __shared__ float red[TI2][4];
    const float4* src = (const float4*)(fm + (size_t)r0 * CC);
    for (int v = t; v < TI2*CC/4; v += 256) ((float4*)rows)[v] = src[v];
    __syncthreads();
    const float4* w4 = (const float4*)(Watt + (size_t)t * CC);
    float acc[TI2];
    #pragma unroll
    for (int i = 0; i < TI2; ++i) acc[i] = 0.f;
    #pragma unroll 4
    for (int k4 = 0; k4 < CC/4; ++k4) {
        float4 w = w4[k4];
        #pragma unroll
        for (int i = 0; i < TI2; ++i) {
            float4 x = *((const float4*)&rows[i][k4*4]);   // broadcast read
            acc[i] += x.x*w.x + x.y*w.y + x.z*w.z + x.w*w.w;
        }
    }
    const float ba = batt[t], wt = Wthr[t];
    const int lane = t & 63, wid = t >> 6;
    #pragma unroll
    for (int i = 0; i < TI2; ++i) {
        float v = acc[i] + ba;
        sc[(size_t)(r0 + i) * CC + t] = v;
        float p = v * wt;
        #pragma unroll
        for (int off = 32; off; off >>= 1) p += __shfl_down(p, off);
        if (lane == 0) red[i][wid] = p;
    }
    __syncthreads();
    if (t < TI2) T[r0 + t] = red[t][0] + red[t][1] + red[t][2] + red[t][3] + bthr[0];
}

// ---------------------------------------------------------------------------
// K3: D[j] = sum_i exp( relu( exp(-relu(|ei-ej|^2)) - T[j] ) )
// grid: B * 64 jtiles * SPLIT blocks of 256 threads.
// Block: fixed 64-column tile, loops over its i-range; atomicAdd into D.
// ---------------------------------------------------------------------------
__global__ __launch_bounds__(256) void k_colsum(const float* __restrict__ emb,
    const float* __restrict__ sqn, const float* __restrict__ T,
    float* __restrict__ D)
{
    const int bid = blockIdx.x;
    const int split = bid & (SPLIT-1);
    const int jt = (bid >> 2) & 63;
    const int b = bid >> 8;
    const int t = threadIdx.x;
    const size_t jbase = (size_t)b*HW + jt*TJ;
    __shared__ float ej[TJ][EPAD];
    __shared__ float ei[TI][EPAD];
    __shared__ float sqnj[TJ], Tj[TJ], colsum[TJ];
    __shared__ float sqni[TI];
    for (int v = t; v < TJ*FC/4; v += 256) {
        int jj = v >> 4, k4 = v & 15;
        *((float4*)&ej[jj][k4*4]) = ((const float4*)(emb + (jbase+jj)*FC))[k4];
    }
    if (t < TJ) { sqnj[t] = sqn[jbase+t]; Tj[t] = T[jbase+t]; colsum[t] = 0.f; }
    __syncthreads();

    const int jjA = t & 31;          // columns jjA and jjA+32
    const int iiB = (t >> 5) * 4;    // 4 rows
    const float sq0 = sqnj[jjA], sq1 = sqnj[jjA+32];
    const float t0 = Tj[jjA], t1 = Tj[jjA+32];
    float csum0 = 0.f, csum1 = 0.f;
    const int itiles = HW / TI / SPLIT;
    for (int itt = 0; itt < itiles; ++itt) {
        const size_t ibase = (size_t)b*HW + (size_t)(split*itiles + itt)*TI;
        for (int v = t; v < TI*FC/4; v += 256) {
            int ii = v >> 4, k4 = v & 15;
            *((float4*)&ei[ii][k4*4]) = ((const float4*)(emb + (ibase+ii)*FC))[k4];
        }
        if (t < TI) sqni[t] = sqn[ibase+t];
        __syncthreads();
        float dot[4][2] = {};
        #pragma unroll
        for (int k4 = 0; k4 < FC/4; ++k4) {
            float4 e0 = *((const float4*)&ej[jjA][k4*4]);
            float4 e1 = *((const float4*)&ej[jjA+32][k4*4]);
            #pragma unroll
            for (int a = 0; a < 4; ++a) {
                float4 x = *((const float4*)&ei[iiB+a][k4*4]);
                dot[a][0] += x.x*e0.x + x.y*e0.y + x.z*e0.z + x.w*e0.w;
                dot[a][1] += x.x*e1.x + x.y*e1.y + x.z*e1.z + x.w*e1.w;
            }
        }
        #pragma unroll
        for (int a = 0; a < 4; ++a) {
            float sn = sqni[iiB+a];
            float d0 = fmaxf(sn + sq0 - 2.f*dot[a][0], 0.f);
            csum0 += __expf(fmaxf(__expf(-d0) - t0, 0.f));
            float d1 = fmaxf(sn + sq1 - 2.f*dot[a][1], 0.f);
            csum1 += __expf(fmaxf(__expf(-d1) - t1, 0.f));
        }
        __syncthreads();
    }
    atomicAdd(&colsum[jjA], csum0);
    atomicAdd(&colsum[jjA+32], csum1);
    __syncthreads();
    if (t < TJ) atomicAdd(&D[jbase + t], colsum[t]);
}

// ---------------------------------------------------------------------------
// K5: out[i,c] = fm[i,c] + sum_j (exp(A[i,j]) / D[j]) * sc[j,c]
// grid: B*(HW/TI) = 512 blocks of 256 threads. TI=32 rows per block,
// loop over all 64 j-tiles; score tile -> LDS, then PV accumulation.
// ---------------------------------------------------------------------------
__global__ __launch_bounds__(256) void k_attn(const float* __restrict__ fm,
    const float* __restrict__ emb, const float* __restrict__ sqn,
    const float* __restrict__ T, const float* __restrict__ D,
    const float* __restrict__ sc, float* __restrict__ out)
{
    const int bid = blockIdx.x;
    const int b = bid >> 7;
    const int i0 = (bid & 127) * TI;
    const int t = threadIdx.x;
    const size_t ibase = (size_t)b*HW + i0;
    __shared__ float ei[TI][EPAD];
    __shared__ float ej[TJ][EPAD];
    __shared__ float sqni[TI];
    __shared__ float sqnj[TJ], Tj[TJ], iDj[TJ];
    __shared__ float s_lds[TJ][SPAD];
    for (int v = t; v < TI*FC/4; v += 256) {
        int ii = v >> 4, k4 = v & 15;
        *((float4*)&ei[ii][k4*4]) = ((const float4*)(emb + (ibase+ii)*FC))[k4];
    }
    if (t < TI) sqni[t] = sqn[ibase+t];

    const int jjA = t & 31;          // score mapping: columns jjA, jjA+32
    const int iiB = (t >> 5) * 4;    // score mapping: 4 rows
    const int c0 = (t & 63) * 4;     // PV mapping: 4 consecutive channels
    const int ii0 = (t >> 6) * 8;    // PV mapping: 8 rows
    float acc[8][4] = {};

    for (int jt = 0; jt < HW/TJ; ++jt) {
        const size_t jbase = (size_t)b*HW + (size_t)jt*TJ;
        for (int v = t; v < TJ*FC/4; v += 256) {
            int jj = v >> 4, k4 = v & 15;
            *((float4*)&ej[jj][k4*4]) = ((const float4*)(emb + (jbase+jj)*FC))[k4];
        }
        if (t < TJ) { sqnj[t] = sqn[jbase+t]; Tj[t] = T[jbase+t]; iDj[t] = 1.0f / D[jbase+t]; }
        __syncthreads();
        float dot[4][2] = {};
        #pragma unroll
        for (int k4 = 0; k4 < FC/4; ++k4) {
            float4 e0 = *((const float4*)&ej[jjA][k4*4]);
            float4 e1 = *((const float4*)&ej[jjA+32][k4*4]);
            #pragma unroll
            for (int a = 0; a < 4; ++a) {
                float4 x = *((const float4*)&ei[iiB+a][k4*4]);
                dot[a][0] += x.x*e0.x + x.y*e0.y + x.z*e0.z + x.w*e0.w;
                dot[a][1] += x.x*e1.x + x.y*e1.y + x.z*e1.z + x.w*e1.w;
            }
        }
        const float sq0 = sqnj[jjA], sq1 = sqnj[jjA+32];
        const float t0 = Tj[jjA], t1 = Tj[jjA+32];
        const float id0 = iDj[jjA], id1 = iDj[jjA+32];
        #pragma unroll
        for (int a = 0; a < 4; ++a) {
            float sn = sqni[iiB+a];
            float d0 = fmaxf(sn + sq0 - 2.f*dot[a][0], 0.f);
            s_lds[jjA][iiB+a] = __expf(fmaxf(__expf(-d0) - t0, 0.f)) * id0;
            float d1 = fmaxf(sn + sq1 - 2.f*dot[a][1], 0.f);
            s_lds[jjA+32][iiB+a] = __expf(fmaxf(__expf(-d1) - t1, 0.f)) * id1;
        }
        __syncthreads();
        const float4* scp = (const float4*)(sc + jbase*CC);
        #pragma unroll 4
        for (int jj = 0; jj < TJ; ++jj) {
            float4 v = scp[jj*(CC/4) + (c0 >> 2)];
            float4 sa = *((const float4*)&s_lds[jj][ii0]);
            float4 sb = *((const float4*)&s_lds[jj][ii0+4]);
            float s8[8] = {sa.x,sa.y,sa.z,sa.w,sb.x,sb.y,sb.z,sb.w};
            #pragma unroll
            for (int q = 0; q < 8; ++q) {
                acc[q][0] += s8[q]*v.x; acc[q][1] += s8[q]*v.y;
                acc[q][2] += s8[q]*v.z; acc[q][3] += s8[q]*v.w;
            }
        }
        // no trailing barrier needed: next iter's ej/sqnj loads don't touch
        // s_lds/sc, and the post-load barrier orders s_lds reuse.
    }
    #pragma unroll
    for (int q = 0; q < 8; ++q) {
        const size_t r = ibase + ii0 + q;
        float4 f = *((const float4*)(fm + r*CC + c0));
        float4 o;
        o.x = f.x + acc[q][0]; o.y = f.y + acc[q][1];
        o.z = f.z + acc[q][2]; o.w = f.w + acc[q][3];
        *((float4*)(out + r*CC + c0)) = o;
    }
}

extern "C" void kernel_launch(void* const* d_in, const int* in_sizes, int n_in,
                              void* d_out, int out_size, void* d_ws, size_t ws_size,
                              hipStream_t stream)
{
    const float* fm   = (const float*)d_in[0];
    const float* Wemb = (const float*)d_in[1];
    const float* bemb = (const float*)d_in[2];
    const float* Watt = (const float*)d_in[3];
    const float* batt = (const float*)d_in[4];
    const float* Wthr = (const float*)d_in[5];
    const float* bthr = (const float*)d_in[6];
    float* ws  = (float*)d_ws;
    float* emb = ws + OFF_EMB;
    float* sc  = ws + OFF_SC;
    float* sqn = ws + OFF_SQN;
    float* T   = ws + OFF_T;
    float* D   = ws + OFF_D;
    float* out = (float*)d_out;

    k_emb   <<<BB*HW,        64,  0, stream>>>(fm, Wemb, bemb, emb, sqn, D);
    k_sc    <<<BB*HW/TI2,    256, 0, stream>>>(fm, Watt, batt, Wthr, bthr, sc, T);
    k_colsum<<<BB*64*SPLIT,  256, 0, stream>>>(emb, sqn, T, D);
    k_attn  <<<BB*(HW/TI),   256, 0, stream>>>(fm, emb, sqn, T, D, sc, out);
}

// Round 2
// 312.048 us; speedup vs baseline: 3.3940x; 3.3940x over previous
//
#include <hip/hip_runtime.h>
#include <hip/hip_bf16.h>
#include <math.h>

typedef __attribute__((ext_vector_type(8))) short short8;
typedef __attribute__((ext_vector_type(4))) float f32x4;

#define BB 4
#define HW 4096
#define CC 256
#define FC 64
#define EPADS 72   // padded bf16 elems per 64-elem emb row in LDS (144 B)
#define PPADS 72   // P tile row pad

// ws byte offsets
#define OFF_EMB 0                        // short[16384*64]    = 2 MB
#define OFF_SCT (2*1024*1024)            // short[4*256*4096]  = 8 MB
#define OFF_SQN (OFF_SCT + 8*1024*1024)  // float[16384]
#define OFF_T   (OFF_SQN + 64*1024)
#define OFF_D   (OFF_T   + 64*1024)

static __device__ __forceinline__ short f2bf(float f) {
    __hip_bfloat16 h = __float2bfloat16(f);
    return *reinterpret_cast<short*>(&h);
}

// ---------------------------------------------------------------------------
// K1: emb_bf[r][f] = bf16(fm[r,:] . W_emb[f,:] + b_emb[f]);
//     sqn[r] = sum_f bf16val^2  (so MFMA dot matches sqn exactly); D[r]=0.
// grid: 1024 blocks x 256 thr; 16 rows/block; wave rg handles rows rg+4i.
// ---------------------------------------------------------------------------
#define ER 16
__global__ __launch_bounds__(256) void k_emb(const float* __restrict__ fm,
    const float* __restrict__ Wemb, const float* __restrict__ bemb,
    short* __restrict__ emb, float* __restrict__ sqn, float* __restrict__ D)
{
    const int r0 = blockIdx.x * ER;
    const int t = threadIdx.x;
    const int f = t & 63, rg = t >> 6;
    __shared__ float rows[ER][CC];
    const float4* src = (const float4*)(fm + (size_t)r0 * CC);
    for (int v = t; v < ER*CC/4; v += 256) ((float4*)rows)[v] = src[v];
    __syncthreads();
    const float4* w4 = (const float4*)(Wemb + (size_t)f * CC);
    float acc[4] = {0.f,0.f,0.f,0.f};
    for (int k4 = 0; k4 < CC/4; ++k4) {
        float4 w = w4[k4];
        #pragma unroll
        for (int i = 0; i < 4; ++i) {
            float4 x = *((const float4*)&rows[rg + i*4][k4*4]);
            acc[i] += x.x*w.x + x.y*w.y + x.z*w.z + x.w*w.w;
        }
    }
    const float bb = bemb[f];
    #pragma unroll
    for (int i = 0; i < 4; ++i) {
        int r = r0 + rg + i*4;
        short bv = f2bf(acc[i] + bb);
        emb[(size_t)r*FC + f] = bv;
        __hip_bfloat16 hb = *reinterpret_cast<__hip_bfloat16*>(&bv);
        float sf = __bfloat162float(hb);
        float q = sf*sf;
        #pragma unroll
        for (int off = 32; off; off >>= 1) q += __shfl_down(q, off);
        if (f == 0) { sqn[r] = q; D[r] = 0.f; }
    }
}

// ---------------------------------------------------------------------------
// K2: shortcut + threshold. Emits sc TRANSPOSED bf16: sct[b][c][j], and T[r].
// grid: 1024 blocks x 256 thr (thread = channel c); 16 rows/block.
// ---------------------------------------------------------------------------
#define SR 16
__global__ __launch_bounds__(256) void k_sc(const float* __restrict__ fm,
    const float* __restrict__ Watt, const float* __restrict__ batt,
    const float* __restrict__ Wthr, const float* __restrict__ bthr,
    short* __restrict__ sct, float* __restrict__ T)
{
    const int r0 = blockIdx.x * SR;
    const int t = threadIdx.x;
    __shared__ float rows[SR][CC];
    __shared__ float red[SR][4];
    const float4* src = (const float4*)(fm + (size_t)r0*CC);
    for (int v = t; v < SR*CC/4; v += 256) ((float4*)rows)[v] = src[v];
    __syncthreads();
    const float4* w4 = (const float4*)(Watt + (size_t)t*CC);
    float acc[SR];
    #pragma unroll
    for (int i = 0; i < SR; ++i) acc[i] = 0.f;
    for (int k4 = 0; k4 < CC/4; ++k4) {
        float4 w = w4[k4];
        #pragma unroll
        for (int i = 0; i < SR; ++i) {
            float4 x = *((const float4*)&rows[i][k4*4]);
            acc[i] += x.x*w.x + x.y*w.y + x.z*w.z + x.w*w.w;
        }
    }
    const float ba = batt[t], wt = Wthr[t];
    const int lane = t & 63, wid = t >> 6;
    short sv[SR];
    #pragma unroll
    for (int i = 0; i < SR; ++i) {
        float v = acc[i] + ba;
        sv[i] = f2bf(v);
        float p = v * wt;
        #pragma unroll
        for (int off = 32; off; off >>= 1) p += __shfl_down(p, off);
        if (lane == 0) red[i][wid] = p;
    }
    const int b = r0 >> 12, rr = r0 & (HW-1);
    short8 pk0, pk1;
    #pragma unroll
    for (int i = 0; i < 8; ++i) { pk0[i] = sv[i]; pk1[i] = sv[8+i]; }
    short* dst = sct + ((size_t)b*CC + t)*HW + rr;
    *((short8*)dst) = pk0;
    *((short8*)(dst + 8)) = pk1;
    __syncthreads();
    if (t < SR) T[r0 + t] = red[t][0]+red[t][1]+red[t][2]+red[t][3] + bthr[0];
}

// ---------------------------------------------------------------------------
// K3: D[j] += sum_i exp(relu(exp(-relu(|ei-ej|^2)) - T[j]))  (MFMA score)
// grid: 4*64*8 = 2048 blocks x 256 thr. j-tile 64, i-split 8 (8 i-tiles of 64).
// ---------------------------------------------------------------------------
#define CSPLIT 8
#define CBI 64
__global__ __launch_bounds__(256) void k_colsum(const short* __restrict__ emb,
    const float* __restrict__ sqn, const float* __restrict__ T,
    float* __restrict__ D)
{
    const int bid = blockIdx.x;
    const int split = bid & (CSPLIT-1);
    const int jt = (bid >> 3) & 63;
    const int b = bid >> 9;
    const int t = threadIdx.x;
    const int w = t >> 6, lane = t & 63, g = lane >> 4, n16 = lane & 15;
    const size_t jbase = (size_t)b*HW + jt*64;
    __shared__ short ej[64][EPADS];
    __shared__ short ei[CBI][EPADS];
    __shared__ float sqni[CBI];
    for (int v = t; v < 64*8; v += 256) {
        int rr = v >> 3, ch = v & 7;
        *((short8*)&ej[rr][ch*8]) = *((const short8*)(emb + (jbase+rr)*FC + ch*8));
    }
    const int jl = w*16 + n16;
    const float sqj = sqn[jbase + jl];
    const float tj  = T[jbase + jl];
    float csum = 0.f;
    __syncthreads();
    const short8 bf0 = *((const short8*)&ej[jl][g*8]);
    const short8 bf1 = *((const short8*)&ej[jl][32 + g*8]);
    const int iters = HW / CBI / CSPLIT;  // 8
    for (int it = 0; it < iters; ++it) {
        const size_t ibase = (size_t)b*HW + (size_t)(split*iters + it)*CBI;
        for (int v = t; v < CBI*8; v += 256) {
            int rr = v >> 3, ch = v & 7;
            *((short8*)&ei[rr][ch*8]) = *((const short8*)(emb + (ibase+rr)*FC + ch*8));
        }
        if (t < CBI) sqni[t] = sqn[ibase + t];
        __syncthreads();
        #pragma unroll
        for (int m = 0; m < 4; ++m) {
            f32x4 dot = {0.f,0.f,0.f,0.f};
            short8 a0 = *((const short8*)&ei[m*16 + n16][g*8]);
            short8 a1 = *((const short8*)&ei[m*16 + n16][32 + g*8]);
            dot = __builtin_amdgcn_mfma_f32_16x16x32_bf16(a0, bf0, dot, 0, 0, 0);
            dot = __builtin_amdgcn_mfma_f32_16x16x32_bf16(a1, bf1, dot, 0, 0, 0);
            #pragma unroll
            for (int r = 0; r < 4; ++r) {
                float sn = sqni[m*16 + g*4 + r];
                float d = fmaxf(sn + sqj - 2.f*dot[r], 0.f);
                csum += __expf(fmaxf(__expf(-d) - tj, 0.f));
            }
        }
        __syncthreads();
    }
    csum += __shfl_xor(csum, 16);
    csum += __shfl_xor(csum, 32);
    if (g == 0) atomicAdd(&D[jbase + jl], csum);
}

// ---------------------------------------------------------------------------
// K4: fused score + softmax-normalize + PV, out = fm + P @ sc.
// grid: 512 blocks (XCD-swizzled) x 256 thr. 32 rows/block, j-loop of 64.
// wave w: score cols w*16..+15 (all 32 rows); PV channels w*64..+63.
// ---------------------------------------------------------------------------
__global__ __launch_bounds__(256) void k_attn(const float* __restrict__ fm,
    const short* __restrict__ emb, const float* __restrict__ sqn,
    const float* __restrict__ T, const float* __restrict__ D,
    const short* __restrict__ sct, float* __restrict__ out)
{
    // bijective XCD-chunked swizzle (512 % 8 == 0): keep a batch per XCD pair
    const int bid = (blockIdx.x & 7) * 64 + (blockIdx.x >> 3);
    const int b = bid >> 7;
    const int i0 = (bid & 127) * 32;
    const int t = threadIdx.x;
    const int w = t >> 6, lane = t & 63, g = lane >> 4, n16 = lane & 15;
    const size_t ibase = (size_t)b*HW + i0;
    __shared__ short ei[32][EPADS];
    __shared__ short ej[64][EPADS];
    __shared__ short P[32][PPADS];
    __shared__ float sqni_l[32];
    for (int v = t; v < 32*8; v += 256) {
        int rr = v >> 3, ch = v & 7;
        *((short8*)&ei[rr][ch*8]) = *((const short8*)(emb + (ibase+rr)*FC + ch*8));
    }
    if (t < 32) sqni_l[t] = sqn[ibase + t];

    f32x4 acc[2][4];
    #pragma unroll
    for (int m = 0; m < 2; ++m)
        #pragma unroll
        for (int nn = 0; nn < 4; ++nn) acc[m][nn] = (f32x4){0.f,0.f,0.f,0.f};

    __syncthreads();
    short8 sa0[2], sa1[2];
    float sni[2][4];
    #pragma unroll
    for (int m = 0; m < 2; ++m) {
        sa0[m] = *((const short8*)&ei[m*16 + n16][g*8]);
        sa1[m] = *((const short8*)&ei[m*16 + n16][32 + g*8]);
        #pragma unroll
        for (int r = 0; r < 4; ++r) sni[m][r] = sqni_l[m*16 + g*4 + r];
    }
    const short* sctb = sct + ((size_t)b*CC + (size_t)w*64)*HW;
    const int jl = w*16 + n16;

    for (int jt = 0; jt < HW/64; ++jt) {
        const size_t jbase = (size_t)b*HW + (size_t)jt*64;
        for (int v = t; v < 64*8; v += 256) {
            int rr = v >> 3, ch = v & 7;
            *((short8*)&ej[rr][ch*8]) = *((const short8*)(emb + (jbase+rr)*FC + ch*8));
        }
        const float sqj = sqn[jbase + jl];
        const float tj  = T[jbase + jl];
        const float iD  = 1.0f / D[jbase + jl];
        __syncthreads();
        short8 b0 = *((const short8*)&ej[jl][g*8]);
        short8 b1 = *((const short8*)&ej[jl][32 + g*8]);
        #pragma unroll
        for (int m = 0; m < 2; ++m) {
            f32x4 dot = {0.f,0.f,0.f,0.f};
            dot = __builtin_amdgcn_mfma_f32_16x16x32_bf16(sa0[m], b0, dot, 0, 0, 0);
            dot = __builtin_amdgcn_mfma_f32_16x16x32_bf16(sa1[m], b1, dot, 0, 0, 0);
            #pragma unroll
            for (int r = 0; r < 4; ++r) {
                float d = fmaxf(sni[m][r] + sqj - 2.f*dot[r], 0.f);
                float p = __expf(fmaxf(__expf(-d) - tj, 0.f)) * iD;
                P[m*16 + g*4 + r][jl] = f2bf(p);
            }
        }
        __syncthreads();
        #pragma unroll
        for (int h = 0; h < 2; ++h) {
            short8 pa[2];
            #pragma unroll
            for (int m = 0; m < 2; ++m)
                pa[m] = *((const short8*)&P[m*16 + n16][h*32 + g*8]);
            #pragma unroll
            for (int nn = 0; nn < 4; ++nn) {
                const short* bp = sctb + (size_t)(nn*16 + n16)*HW + jt*64 + h*32 + g*8;
                short8 bv = *((const short8*)bp);
                #pragma unroll
                for (int m = 0; m < 2; ++m)
                    acc[m][nn] = __builtin_amdgcn_mfma_f32_16x16x32_bf16(pa[m], bv, acc[m][nn], 0, 0, 0);
            }
        }
        __syncthreads();
    }
    #pragma unroll
    for (int m = 0; m < 2; ++m)
        #pragma unroll
        for (int r = 0; r < 4; ++r) {
            size_t row = ibase + m*16 + g*4 + r;
            #pragma unroll
            for (int nn = 0; nn < 4; ++nn) {
                int c = w*64 + nn*16 + n16;
                out[row*CC + c] = fm[row*CC + c] + acc[m][nn][r];
            }
        }
}

extern "C" void kernel_launch(void* const* d_in, const int* in_sizes, int n_in,
                              void* d_out, int out_size, void* d_ws, size_t ws_size,
                              hipStream_t stream)
{
    const float* fm   = (const float*)d_in[0];
    const float* Wemb = (const float*)d_in[1];
    const float* bemb = (const float*)d_in[2];
    const float* Watt = (const float*)d_in[3];
    const float* batt = (const float*)d_in[4];
    const float* Wthr = (const float*)d_in[5];
    const float* bthr = (const float*)d_in[6];
    char* ws = (char*)d_ws;
    short* emb = (short*)(ws + OFF_EMB);
    short* sct = (short*)(ws + OFF_SCT);
    float* sqn = (float*)(ws + OFF_SQN);
    float* T   = (float*)(ws + OFF_T);
    float* D   = (float*)(ws + OFF_D);
    float* out = (float*)d_out;

    k_emb   <<<BB*HW/ER,      256, 0, stream>>>(fm, Wemb, bemb, emb, sqn, D);
    k_sc    <<<BB*HW/SR,      256, 0, stream>>>(fm, Watt, batt, Wthr, bthr, sct, T);
    k_colsum<<<BB*64*CSPLIT,  256, 0, stream>>>(emb, sqn, T, D);
    k_attn  <<<BB*(HW/32),    256, 0, stream>>>(fm, emb, sqn, T, D, sct, out);
}

// Round 3
// 153.494 us; speedup vs baseline: 6.8999x; 2.0330x over previous
//
#include <hip/hip_runtime.h>
#include <hip/hip_bf16.h>
#include <math.h>

typedef __attribute__((ext_vector_type(8))) short short8;
typedef __attribute__((ext_vector_type(4))) float f32x4;

#define BB 4
#define HW 4096
#define CC 256
#define FC 64
#define L2E 1.4426950408889634f

// ws byte offsets
#define OFF_EMB   0                      // short[16384*64]   = 2 MB
#define OFF_SCT2  (2*1024*1024)          // short[4*64*8*256*8] = 8 MB
#define OFF_SQN   (OFF_SCT2 + 8*1024*1024)
#define OFF_T     (OFF_SQN + 65536)
#define OFF_D     (OFF_T   + 65536)
#define OFF_WEMB2 (OFF_D   + 65536)      // short[32*64*8] = 32 KB
#define OFF_WATT2 (OFF_WEMB2 + 32768)    // short[32*256*8] = 128 KB

static __device__ __forceinline__ short f2bf(float f) {
    __hip_bfloat16 h = __float2bfloat16(f);
    return *reinterpret_cast<short*>(&h);
}
static __device__ __forceinline__ float bf2f(short s) {
    __hip_bfloat16 h = *reinterpret_cast<__hip_bfloat16*>(&s);
    return __bfloat162float(h);
}
static __device__ __forceinline__ float fexp2(float x) {
#if __has_builtin(__builtin_amdgcn_exp2f)
    return __builtin_amdgcn_exp2f(x);
#else
    float r; asm("v_exp_f32 %0, %1" : "=v"(r) : "v"(x)); return r;
#endif
}
static __device__ __forceinline__ float frcp(float x) {
#if __has_builtin(__builtin_amdgcn_rcpf)
    return __builtin_amdgcn_rcpf(x);
#else
    return 1.0f / x;
#endif
}

// ---------------------------------------------------------------------------
// K0: weight conversion to tiled bf16 B-fragment layouts + D zero.
// Watt2[kc(32)][d(256)][e(8)] = bf16(Watt[d][kc*8+e]); Wemb2[kc][f(64)][e].
// grid 320 x 256.
// ---------------------------------------------------------------------------
__global__ __launch_bounds__(256) void k_prep(const float* __restrict__ Wemb,
    const float* __restrict__ Watt, short* __restrict__ Wemb2,
    short* __restrict__ Watt2, float* __restrict__ D)
{
    const int bid = blockIdx.x, t = threadIdx.x;
    if (bid < 256) {
        Watt2[(size_t)(t>>3)*2048 + bid*8 + (t&7)] = f2bf(Watt[(size_t)bid*256 + t]);
        if (bid < 64) D[bid*256 + t] = 0.f;
    } else {
        const int f = bid - 256;
        Wemb2[(size_t)(t>>3)*512 + f*8 + (t&7)] = f2bf(Wemb[(size_t)f*256 + t]);
    }
}

// ---------------------------------------------------------------------------
// K1 (fused emb + shortcut + threshold, all MFMA):
// per block: 16 rows. wave w: sct channels w*64..+63, emb features w*16..+15.
// Outputs: emb bf16 [r][64], sct2 tiled bf16, sqn (from rounded emb), T.
// grid 1024 x 256.
// ---------------------------------------------------------------------------
__global__ __launch_bounds__(256) void k_front(const float* __restrict__ fm,
    const short* __restrict__ Wemb2, const short* __restrict__ Watt2,
    const float* __restrict__ bemb, const float* __restrict__ batt,
    const float* __restrict__ wthr, const float* __restrict__ bthr,
    short* __restrict__ emb, short* __restrict__ sct2,
    float* __restrict__ sqn, float* __restrict__ T)
{
    const int blk = blockIdx.x;
    const int b = blk >> 8;
    const int r0 = (blk & 255) * 16;
    const int t = threadIdx.x;
    const int w = t >> 6, lane = t & 63, g = lane >> 4, n16 = lane & 15;
    __shared__ short fmt[16*256];        // swizzled bf16 A-tile, rows 512B
    __shared__ float tred[16][4];
    __shared__ float qred[16][4];
    // stage fm -> bf16 (rows 16 x 256): 512 chunks of 8, 2/thread
    #pragma unroll
    for (int v = t; v < 512; v += 256) {
        const int row = v >> 5, c32 = v & 31;
        const float4* src = (const float4*)(fm + ((size_t)b*HW + r0 + row)*CC + c32*8);
        float4 x0 = src[0], x1 = src[1];
        short8 pv;
        pv[0]=f2bf(x0.x); pv[1]=f2bf(x0.y); pv[2]=f2bf(x0.z); pv[3]=f2bf(x0.w);
        pv[4]=f2bf(x1.x); pv[5]=f2bf(x1.y); pv[6]=f2bf(x1.z); pv[7]=f2bf(x1.w);
        *(short8*)((char*)fmt + row*512 + ((c32*16) ^ ((row&7)<<4))) = pv;
    }
    __syncthreads();
    const int cb = w*64, fb = w*16;
    f32x4 acc[4], acce;
    #pragma unroll
    for (int nn = 0; nn < 4; ++nn) acc[nn] = (f32x4){0.f,0.f,0.f,0.f};
    acce = (f32x4){0.f,0.f,0.f,0.f};
    #pragma unroll
    for (int kk = 0; kk < 8; ++kk) {
        const int kc = kk*4 + g;
        short8 a = *(const short8*)((const char*)fmt + n16*512 + ((kc*16) ^ ((n16&7)<<4)));
        const short* wb = Watt2 + (size_t)kc*2048 + (cb + n16)*8;
        #pragma unroll
        for (int nn = 0; nn < 4; ++nn) {
            short8 bv = *(const short8*)(wb + nn*128);
            acc[nn] = __builtin_amdgcn_mfma_f32_16x16x32_bf16(a, bv, acc[nn], 0, 0, 0);
        }
        short8 be = *(const short8*)(Wemb2 + (size_t)kc*512 + (fb + n16)*8);
        acce = __builtin_amdgcn_mfma_f32_16x16x32_bf16(a, be, acce, 0, 0, 0);
    }
    // ---- sct epilogue: bias, T partial, pack rows-pairs to sct2 ----
    float tp[4] = {0.f,0.f,0.f,0.f};
    const int jt_ = r0 >> 6;
    const int jc0 = (r0 & 63) >> 3;
    const size_t tilebase = ((size_t)b*64 + jt_)*8;
    #pragma unroll
    for (int nn = 0; nn < 4; ++nn) {
        const int ch = cb + nn*16 + n16;
        const float ba_ = batt[ch], wt_ = wthr[ch];
        float v[4];
        #pragma unroll
        for (int r = 0; r < 4; ++r) { v[r] = acc[nn][r] + ba_; tp[r] = fmaf(v[r], wt_, tp[r]); }
        const int jc = jc0 + (g >> 1);
        const int jw0 = (g & 1)*4;
        short* dstp = sct2 + (tilebase + jc)*2048 + (size_t)ch*8;
        unsigned u01 = (unsigned short)f2bf(v[0]) | ((unsigned)(unsigned short)f2bf(v[1]) << 16);
        unsigned u23 = (unsigned short)f2bf(v[2]) | ((unsigned)(unsigned short)f2bf(v[3]) << 16);
        *(unsigned*)(dstp + jw0)     = u01;
        *(unsigned*)(dstp + jw0 + 2) = u23;
    }
    #pragma unroll
    for (int r = 0; r < 4; ++r)
        #pragma unroll
        for (int off = 1; off <= 8; off <<= 1) tp[r] += __shfl_xor(tp[r], off);
    // ---- emb epilogue: bias, round, store, sqn partial ----
    const int f = fb + n16;
    const float be_ = bemb[f];
    float qp[4];
    #pragma unroll
    for (int r = 0; r < 4; ++r) {
        short bv = f2bf(acce[r] + be_);
        emb[((size_t)b*HW + r0 + g*4 + r)*FC + f] = bv;
        float ef = bf2f(bv);
        qp[r] = ef*ef;
        #pragma unroll
        for (int off = 1; off <= 8; off <<= 1) qp[r] += __shfl_xor(qp[r], off);
    }
    if (n16 == 0) {
        #pragma unroll
        for (int r = 0; r < 4; ++r) { tred[g*4+r][w] = tp[r]; qred[g*4+r][w] = qp[r]; }
    }
    __syncthreads();
    if (t < 16) {
        T[(size_t)b*HW + r0 + t]   = tred[t][0]+tred[t][1]+tred[t][2]+tred[t][3] + bthr[0];
        sqn[(size_t)b*HW + r0 + t] = qred[t][0]+qred[t][1]+qred[t][2]+qred[t][3];
    }
}

// ---------------------------------------------------------------------------
// K2: column sums D[j] (softmax denominator over i), MFMA score + exp2 chain.
// grid 4*64*8 = 2048 x 256. XOR-swizzled LDS (2-way max).
// ---------------------------------------------------------------------------
__global__ __launch_bounds__(256) void k_colsum(const short* __restrict__ emb,
    const float* __restrict__ sqn, const float* __restrict__ T,
    float* __restrict__ D)
{
    const int bid = blockIdx.x;
    const int split = bid & 7, jt = (bid >> 3) & 63, b = bid >> 9;
    const int t = threadIdx.x, w = t >> 6, lane = t & 63, g = lane >> 4, n16 = lane & 15;
    const size_t jbase = (size_t)b*HW + jt*64;
    __shared__ short ej[64*64];
    __shared__ short ei[64*64];
    __shared__ float sqni[64];
    #pragma unroll
    for (int v = t; v < 512; v += 256) {
        const int row = v >> 3, c8 = v & 7;
        short8 x = *(const short8*)(emb + (jbase + row)*FC + c8*8);
        *(short8*)((char*)ej + row*128 + ((c8*16) ^ ((row&7)<<4))) = x;
    }
    const int jl = w*16 + n16;
    const float sqjL = -L2E * sqn[jbase + jl];
    const float tjL  = -L2E * T[jbase + jl];
    __syncthreads();
    const short8 b0 = *(const short8*)((const char*)ej + jl*128 + (((g  )*16) ^ ((jl&7)<<4)));
    const short8 b1 = *(const short8*)((const char*)ej + jl*128 + (((g+4)*16) ^ ((jl&7)<<4)));
    float csum = 0.f;
    for (int it = 0; it < 8; ++it) {
        const size_t ibase = (size_t)b*HW + (size_t)(split*8 + it)*64;
        __syncthreads();
        #pragma unroll
        for (int v = t; v < 512; v += 256) {
            const int row = v >> 3, c8 = v & 7;
            short8 x = *(const short8*)(emb + (ibase + row)*FC + c8*8);
            *(short8*)((char*)ei + row*128 + ((c8*16) ^ ((row&7)<<4))) = x;
        }
        if (t < 64) sqni[t] = sqn[ibase + t];
        __syncthreads();
        #pragma unroll
        for (int m = 0; m < 4; ++m) {
            const int arow = m*16 + n16;
            short8 a0 = *(const short8*)((const char*)ei + arow*128 + (((g  )*16) ^ ((n16&7)<<4)));
            short8 a1 = *(const short8*)((const char*)ei + arow*128 + (((g+4)*16) ^ ((n16&7)<<4)));
            f32x4 dot = {0.f,0.f,0.f,0.f};
            dot = __builtin_amdgcn_mfma_f32_16x16x32_bf16(a0, b0, dot, 0, 0, 0);
            dot = __builtin_amdgcn_mfma_f32_16x16x32_bf16(a1, b1, dot, 0, 0, 0);
            #pragma unroll
            for (int r = 0; r < 4; ++r) {
                float x1 = fminf(fmaf(dot[r], 2.f*L2E, fmaf(-L2E, sqni[m*16 + g*4 + r], sqjL)), 0.f);
                float e1 = fexp2(x1);
                float a_ = fmaxf(fmaf(e1, L2E, tjL), 0.f);
                csum += fexp2(a_);
            }
        }
    }
    csum += __shfl_xor(csum, 16);
    csum += __shfl_xor(csum, 32);
    if (lane < 16) atomicAdd(&D[jbase + jl], csum);
}

// ---------------------------------------------------------------------------
// K3: fused score + normalize + PV.  grid 512 x 512 (8 waves), 32 rows/block.
// wave w: score tile rows (w>>2)*16, cols (w&3)*16; PV rows (w>>2)*16,
// channels (w&3)*64. ej/P XOR-swizzled; sct2 B-frags straight from L2.
// ---------------------------------------------------------------------------
__global__ __launch_bounds__(512) void k_attn(const float* __restrict__ fm,
    const short* __restrict__ emb, const float* __restrict__ sqn,
    const float* __restrict__ T, const float* __restrict__ D,
    const short* __restrict__ sct2, float* __restrict__ out)
{
    const int bid = ((blockIdx.x & 7) << 6) | (blockIdx.x >> 3);  // XCD chunk swizzle
    const int b = bid >> 7;
    const int i0 = (bid & 127) * 32;
    const int t = threadIdx.x, w = t >> 6, lane = t & 63, g = lane >> 4, n16 = lane & 15;
    const int rb = (w >> 2) * 16;
    const int cq = w & 3;
    const size_t ibase = (size_t)b*HW + i0;
    __shared__ short ej[64*64];   // 8 KB
    __shared__ short P[32*64];    // 4 KB
    // Q-side fragments + row norms (registers, once)
    const short8 a0 = *(const short8*)(emb + (ibase + rb + n16)*FC + g*8);
    const short8 a1 = *(const short8*)(emb + (ibase + rb + n16)*FC + g*8 + 32);
    float snL[4];
    #pragma unroll
    for (int r = 0; r < 4; ++r) snL[r] = -L2E * sqn[ibase + rb + g*4 + r];
    const int srow = t >> 3, sc8 = t & 7;
    const int sbyte = srow*128 + ((sc8*16) ^ ((srow&7)<<4));
    const int jl = cq*16 + n16;
    f32x4 acc[4];
    #pragma unroll
    for (int nn = 0; nn < 4; ++nn) acc[nn] = (f32x4){0.f,0.f,0.f,0.f};
    short8 stg = *(const short8*)(emb + ((size_t)b*HW + srow)*FC + sc8*8);  // jt=0
    for (int jt = 0; jt < 64; ++jt) {
        const size_t jbase = (size_t)b*HW + (size_t)jt*64;
        *(short8*)((char*)ej + sbyte) = stg;
        const float sqjL = -L2E * sqn[jbase + jl];
        const float tjL  = -L2E * T[jbase + jl];
        const float iD   = frcp(D[jbase + jl]);
        __syncthreads();   // A: ej ready, prev PV done (P safe to overwrite)
        short8 b0 = *(const short8*)((const char*)ej + jl*128 + (((g  )*16) ^ ((jl&7)<<4)));
        short8 b1 = *(const short8*)((const char*)ej + jl*128 + (((g+4)*16) ^ ((jl&7)<<4)));
        f32x4 dot = {0.f,0.f,0.f,0.f};
        dot = __builtin_amdgcn_mfma_f32_16x16x32_bf16(a0, b0, dot, 0, 0, 0);
        dot = __builtin_amdgcn_mfma_f32_16x16x32_bf16(a1, b1, dot, 0, 0, 0);
        #pragma unroll
        for (int r = 0; r < 4; ++r) {
            float x1 = fminf(fmaf(dot[r], 2.f*L2E, snL[r] + sqjL), 0.f);
            float e1 = fexp2(x1);
            float a_ = fmaxf(fmaf(e1, L2E, tjL), 0.f);
            float p  = fexp2(a_) * iD;
            const int prow = rb + g*4 + r;
            *(short*)((char*)P + prow*128 + (((jl>>3) ^ (prow&7))<<4) + (jl&7)*2) = f2bf(p);
        }
        __syncthreads();   // B: P ready
        if (jt < 63) stg = *(const short8*)(emb + (jbase + 64 + srow)*FC + sc8*8);
        const short* sb = sct2 + (((size_t)b*64 + jt)*8)*2048 + (size_t)(cq*64 + n16)*8;
        #pragma unroll
        for (int h = 0; h < 2; ++h) {
            const int arow = rb + n16;
            short8 pa = *(const short8*)((const char*)P + arow*128 + ((((h*4+g)) ^ (n16&7))<<4));
            #pragma unroll
            for (int nn = 0; nn < 4; ++nn) {
                short8 bv = *(const short8*)(sb + (size_t)(h*4+g)*2048 + nn*128);
                acc[nn] = __builtin_amdgcn_mfma_f32_16x16x32_bf16(pa, bv, acc[nn], 0, 0, 0);
            }
        }
    }
    #pragma unroll
    for (int r = 0; r < 4; ++r) {
        const size_t row = ibase + rb + g*4 + r;
        #pragma unroll
        for (int nn = 0; nn < 4; ++nn) {
            const size_t idx = row*CC + cq*64 + nn*16 + n16;
            out[idx] = fm[idx] + acc[nn][r];
        }
    }
}

extern "C" void kernel_launch(void* const* d_in, const int* in_sizes, int n_in,
                              void* d_out, int out_size, void* d_ws, size_t ws_size,
                              hipStream_t stream)
{
    const float* fm   = (const float*)d_in[0];
    const float* Wemb = (const float*)d_in[1];
    const float* bemb = (const float*)d_in[2];
    const float* Watt = (const float*)d_in[3];
    const float* batt = (const float*)d_in[4];
    const float* Wthr = (const float*)d_in[5];
    const float* bthr = (const float*)d_in[6];
    char* ws = (char*)d_ws;
    short* emb   = (short*)(ws + OFF_EMB);
    short* sct2  = (short*)(ws + OFF_SCT2);
    float* sqn   = (float*)(ws + OFF_SQN);
    float* T     = (float*)(ws + OFF_T);
    float* D     = (float*)(ws + OFF_D);
    short* Wemb2 = (short*)(ws + OFF_WEMB2);
    short* Watt2 = (short*)(ws + OFF_WATT2);
    float* out = (float*)d_out;

    k_prep  <<<320,  256, 0, stream>>>(Wemb, Watt, Wemb2, Watt2, D);
    k_front <<<1024, 256, 0, stream>>>(fm, Wemb2, Watt2, bemb, batt, Wthr, bthr,
                                       emb, sct2, sqn, T);
    k_colsum<<<2048, 256, 0, stream>>>(emb, sqn, T, D);
    k_attn  <<<512,  512, 0, stream>>>(fm, emb, sqn, T, D, sct2, out);
}

// Round 4
// 102.949 us; speedup vs baseline: 10.2877x; 1.4910x over previous
//
#include <hip/hip_runtime.h>
#include <hip/hip_bf16.h>
#include <math.h>

typedef __attribute__((ext_vector_type(8))) short short8;
typedef __attribute__((ext_vector_type(4))) float f32x4;

#define BB 4
#define HW 4096
#define CC 256
#define FC 64
#define L2E 1.4426950408889634f

// ws byte offsets
#define OFF_EMB   0                      // short[16384*64]   = 2 MB
#define OFF_SCT2  (2*1024*1024)          // short[4*64*8*256*8] = 8 MB
#define OFF_SQN   (OFF_SCT2 + 8*1024*1024)
#define OFF_T     (OFF_SQN + 65536)
#define OFF_D     (OFF_T   + 65536)
#define OFF_WEMB2 (OFF_D   + 65536)      // short[32*64*8] = 32 KB
#define OFF_WATT2 (OFF_WEMB2 + 32768)    // short[32*256*8] = 128 KB

static __device__ __forceinline__ short f2bf(float f) {
    __hip_bfloat16 h = __float2bfloat16(f);
    return *reinterpret_cast<short*>(&h);
}
static __device__ __forceinline__ float bf2f(short s) {
    __hip_bfloat16 h = *reinterpret_cast<__hip_bfloat16*>(&s);
    return __bfloat162float(h);
}
static __device__ __forceinline__ float fexp2(float x) {
#if __has_builtin(__builtin_amdgcn_exp2f)
    return __builtin_amdgcn_exp2f(x);
#else
    float r; asm("v_exp_f32 %0, %1" : "=v"(r) : "v"(x)); return r;
#endif
}
static __device__ __forceinline__ float frcp(float x) {
#if __has_builtin(__builtin_amdgcn_rcpf)
    return __builtin_amdgcn_rcpf(x);
#else
    return 1.0f / x;
#endif
}

// ---------------------------------------------------------------------------
// K0: weight conversion to tiled bf16 B-fragment layouts + D zero.
// ---------------------------------------------------------------------------
__global__ __launch_bounds__(256) void k_prep(const float* __restrict__ Wemb,
    const float* __restrict__ Watt, short* __restrict__ Wemb2,
    short* __restrict__ Watt2, float* __restrict__ D)
{
    const int bid = blockIdx.x, t = threadIdx.x;
    if (bid < 256) {
        Watt2[(size_t)(t>>3)*2048 + bid*8 + (t&7)] = f2bf(Watt[(size_t)bid*256 + t]);
        if (bid < 64) D[bid*256 + t] = 0.f;
    } else {
        const int f = bid - 256;
        Wemb2[(size_t)(t>>3)*512 + f*8 + (t&7)] = f2bf(Wemb[(size_t)f*256 + t]);
    }
}

// ---------------------------------------------------------------------------
// K1 (fused emb + shortcut + threshold, all MFMA). grid 1024 x 256.
// ---------------------------------------------------------------------------
__global__ __launch_bounds__(256) void k_front(const float* __restrict__ fm,
    const short* __restrict__ Wemb2, const short* __restrict__ Watt2,
    const float* __restrict__ bemb, const float* __restrict__ batt,
    const float* __restrict__ wthr, const float* __restrict__ bthr,
    short* __restrict__ emb, short* __restrict__ sct2,
    float* __restrict__ sqn, float* __restrict__ T)
{
    const int blk = blockIdx.x;
    const int b = blk >> 8;
    const int r0 = (blk & 255) * 16;
    const int t = threadIdx.x;
    const int w = t >> 6, lane = t & 63, g = lane >> 4, n16 = lane & 15;
    __shared__ short fmt[16*256];
    __shared__ float tred[16][4];
    __shared__ float qred[16][4];
    #pragma unroll
    for (int v = t; v < 512; v += 256) {
        const int row = v >> 5, c32 = v & 31;
        const float4* src = (const float4*)(fm + ((size_t)b*HW + r0 + row)*CC + c32*8);
        float4 x0 = src[0], x1 = src[1];
        short8 pv;
        pv[0]=f2bf(x0.x); pv[1]=f2bf(x0.y); pv[2]=f2bf(x0.z); pv[3]=f2bf(x0.w);
        pv[4]=f2bf(x1.x); pv[5]=f2bf(x1.y); pv[6]=f2bf(x1.z); pv[7]=f2bf(x1.w);
        *(short8*)((char*)fmt + row*512 + ((c32*16) ^ ((row&7)<<4))) = pv;
    }
    __syncthreads();
    const int cb = w*64, fb = w*16;
    f32x4 acc[4], acce;
    #pragma unroll
    for (int nn = 0; nn < 4; ++nn) acc[nn] = (f32x4){0.f,0.f,0.f,0.f};
    acce = (f32x4){0.f,0.f,0.f,0.f};
    #pragma unroll
    for (int kk = 0; kk < 8; ++kk) {
        const int kc = kk*4 + g;
        short8 a = *(const short8*)((const char*)fmt + n16*512 + ((kc*16) ^ ((n16&7)<<4)));
        const short* wb = Watt2 + (size_t)kc*2048 + (cb + n16)*8;
        #pragma unroll
        for (int nn = 0; nn < 4; ++nn) {
            short8 bv = *(const short8*)(wb + nn*128);
            acc[nn] = __builtin_amdgcn_mfma_f32_16x16x32_bf16(a, bv, acc[nn], 0, 0, 0);
        }
        short8 be = *(const short8*)(Wemb2 + (size_t)kc*512 + (fb + n16)*8);
        acce = __builtin_amdgcn_mfma_f32_16x16x32_bf16(a, be, acce, 0, 0, 0);
    }
    float tp[4] = {0.f,0.f,0.f,0.f};
    const int jt_ = r0 >> 6;
    const int jc0 = (r0 & 63) >> 3;
    const size_t tilebase = ((size_t)b*64 + jt_)*8;
    #pragma unroll
    for (int nn = 0; nn < 4; ++nn) {
        const int ch = cb + nn*16 + n16;
        const float ba_ = batt[ch], wt_ = wthr[ch];
        float v[4];
        #pragma unroll
        for (int r = 0; r < 4; ++r) { v[r] = acc[nn][r] + ba_; tp[r] = fmaf(v[r], wt_, tp[r]); }
        const int jc = jc0 + (g >> 1);
        const int jw0 = (g & 1)*4;
        short* dstp = sct2 + (tilebase + jc)*2048 + (size_t)ch*8;
        unsigned u01 = (unsigned short)f2bf(v[0]) | ((unsigned)(unsigned short)f2bf(v[1]) << 16);
        unsigned u23 = (unsigned short)f2bf(v[2]) | ((unsigned)(unsigned short)f2bf(v[3]) << 16);
        *(unsigned*)(dstp + jw0)     = u01;
        *(unsigned*)(dstp + jw0 + 2) = u23;
    }
    #pragma unroll
    for (int r = 0; r < 4; ++r)
        #pragma unroll
        for (int off = 1; off <= 8; off <<= 1) tp[r] += __shfl_xor(tp[r], off);
    const int f = fb + n16;
    const float be_ = bemb[f];
    float qp[4];
    #pragma unroll
    for (int r = 0; r < 4; ++r) {
        short bv = f2bf(acce[r] + be_);
        emb[((size_t)b*HW + r0 + g*4 + r)*FC + f] = bv;
        float ef = bf2f(bv);
        qp[r] = ef*ef;
        #pragma unroll
        for (int off = 1; off <= 8; off <<= 1) qp[r] += __shfl_xor(qp[r], off);
    }
    if (n16 == 0) {
        #pragma unroll
        for (int r = 0; r < 4; ++r) { tred[g*4+r][w] = tp[r]; qred[g*4+r][w] = qp[r]; }
    }
    __syncthreads();
    if (t < 16) {
        T[(size_t)b*HW + r0 + t]   = tred[t][0]+tred[t][1]+tred[t][2]+tred[t][3] + bthr[0];
        sqn[(size_t)b*HW + r0 + t] = qred[t][0]+qred[t][1]+qred[t][2]+qred[t][3];
    }
}

// ---------------------------------------------------------------------------
// K2: column sums D[j]. grid 2048 x 256. 1 barrier/iter, dbuf ei.
// ---------------------------------------------------------------------------
__global__ __launch_bounds__(256) void k_colsum(const short* __restrict__ emb,
    const float* __restrict__ sqn, const float* __restrict__ T,
    float* __restrict__ D)
{
    const int bid = blockIdx.x;
    const int split = bid & 7, jt = (bid >> 3) & 63, b = bid >> 9;
    const int t = threadIdx.x, w = t >> 6, lane = t & 63, g = lane >> 4, n16 = lane & 15;
    const size_t jbase = (size_t)b*HW + jt*64;
    __shared__ short ej[64*64];
    __shared__ short ei[2][64*64];
    __shared__ float sqni[2][64];
    #pragma unroll
    for (int v = t; v < 512; v += 256) {
        const int row = v >> 3, c8 = v & 7;
        short8 x = *(const short8*)(emb + (jbase + row)*FC + c8*8);
        *(short8*)((char*)ej + row*128 + ((c8*16) ^ ((row&7)<<4))) = x;
    }
    const int jl = w*16 + n16;
    const float sqjL = -L2E * sqn[jbase + jl];
    const float tjL  = -L2E * T[jbase + jl];
    const int srow0 = t >> 3, srow1 = (t >> 3) + 32, sc8 = t & 7;
    const int sb0 = srow0*128 + ((sc8*16) ^ ((srow0&7)<<4));
    const int sb1 = srow1*128 + ((sc8*16) ^ ((srow1&7)<<4));
    const size_t base0 = (size_t)b*HW + (size_t)split*512;
    short8 stg0 = *(const short8*)(emb + (base0 + srow0)*FC + sc8*8);
    short8 stg1 = *(const short8*)(emb + (base0 + srow1)*FC + sc8*8);
    float stgq = (t < 64) ? sqn[base0 + t] : 0.f;
    *(short8*)((char*)ei[0] + sb0) = stg0;
    *(short8*)((char*)ei[0] + sb1) = stg1;
    if (t < 64) sqni[0][t] = stgq;
    stg0 = *(const short8*)(emb + (base0 + 64 + srow0)*FC + sc8*8);
    stg1 = *(const short8*)(emb + (base0 + 64 + srow1)*FC + sc8*8);
    stgq = (t < 64) ? sqn[base0 + 64 + t] : 0.f;
    __syncthreads();
    const short8 bf0 = *(const short8*)((const char*)ej + jl*128 + ((g*16)     ^ ((jl&7)<<4)));
    const short8 bf1 = *(const short8*)((const char*)ej + jl*128 + (((g+4)*16) ^ ((jl&7)<<4)));
    float csum = 0.f;
    for (int it = 0; it < 8; ++it) {
        if (it < 7) {
            char* eib = (char*)ei[(it+1)&1];
            *(short8*)(eib + sb0) = stg0;
            *(short8*)(eib + sb1) = stg1;
            if (t < 64) sqni[(it+1)&1][t] = stgq;
            if (it < 6) {
                const size_t nb = base0 + (size_t)(it+2)*64;
                stg0 = *(const short8*)(emb + (nb + srow0)*FC + sc8*8);
                stg1 = *(const short8*)(emb + (nb + srow1)*FC + sc8*8);
                stgq = (t < 64) ? sqn[nb + t] : 0.f;
            }
        }
        const char* eib = (const char*)ei[it&1];
        const float* sqc = sqni[it&1];
        #pragma unroll
        for (int m = 0; m < 4; ++m) {
            const int arow = m*16 + n16;
            short8 a0 = *(const short8*)(eib + arow*128 + ((g*16)     ^ ((arow&7)<<4)));
            short8 a1 = *(const short8*)(eib + arow*128 + (((g+4)*16) ^ ((arow&7)<<4)));
            f32x4 dot = {0.f,0.f,0.f,0.f};
            dot = __builtin_amdgcn_mfma_f32_16x16x32_bf16(a0, bf0, dot, 0, 0, 0);
            dot = __builtin_amdgcn_mfma_f32_16x16x32_bf16(a1, bf1, dot, 0, 0, 0);
            #pragma unroll
            for (int r = 0; r < 4; ++r) {
                float x1 = fminf(fmaf(dot[r], 2.f*L2E, fmaf(-L2E, sqc[m*16 + g*4 + r], sqjL)), 0.f);
                float e1 = fexp2(x1);
                float a_ = fmaxf(fmaf(e1, L2E, tjL), 0.f);
                csum += fexp2(a_);
            }
        }
        __syncthreads();
    }
    csum += __shfl_xor(csum, 16);
    csum += __shfl_xor(csum, 32);
    if (lane < 16) atomicAdd(&D[jbase + jl], csum);
}

// ---------------------------------------------------------------------------
// K3: fused score + normalize + PV. grid 256 x 512. 64 rows/block.
// 1 barrier/jt; dbuf ej + P; B-frags/scalars/staging prefetched 1 jt ahead.
// ---------------------------------------------------------------------------
#define ATTN_ITER(K, bfC, sqC, tC, dC, bfN, sqN, tN, dN)                         \
  {                                                                              \
    const int kn = (K) < 63 ? (K) + 1 : 63;                                      \
    const size_t jbn = bbase + (size_t)kn * 64;                                  \
    sqN = sqn[jbn + jl]; tN = T[jbn + jl]; dN = D[jbn + jl];                     \
    {                                                                            \
      const short* sbn = sct2 + ((size_t)(b*64 + kn)*8)*2048 + (size_t)(w*32 + n16)*8; \
      _Pragma("unroll")                                                          \
      for (int nn = 0; nn < 2; ++nn) {                                           \
        _Pragma("unroll")                                                        \
        for (int kc = 0; kc < 2; ++kc)                                           \
          bfN[nn*2+kc] = *(const short8*)(sbn + (size_t)(kc*4+g)*2048 + nn*128); \
      }                                                                          \
    }                                                                            \
    {                                                                            \
      const float iD   = frcp(dC);                                               \
      const float sqjL = -L2E * sqC;                                             \
      const float tjL  = -L2E * tC;                                              \
      const char* ejb = (const char*)ejlds[(K)&1];                               \
      char* Pb = (char*)Plds[(K)&1];                                             \
      short8 b0 = *(const short8*)(ejb + jl*128 + ((g*16)     ^ ((jl&7)<<4)));   \
      short8 b1 = *(const short8*)(ejb + jl*128 + (((g+4)*16) ^ ((jl&7)<<4)));   \
      _Pragma("unroll")                                                          \
      for (int t2 = 0; t2 < 2; ++t2) {                                           \
        f32x4 dot = {0.f,0.f,0.f,0.f};                                           \
        dot = __builtin_amdgcn_mfma_f32_16x16x32_bf16(aQ0[t2], b0, dot, 0,0,0);  \
        dot = __builtin_amdgcn_mfma_f32_16x16x32_bf16(aQ1[t2], b1, dot, 0,0,0);  \
        _Pragma("unroll")                                                        \
        for (int r = 0; r < 4; ++r) {                                            \
          float x1 = fminf(fmaf(dot[r], 2.f*L2E, snL[t2][r] + sqjL), 0.f);       \
          float e1 = fexp2(x1);                                                  \
          float a_ = fmaxf(fmaf(e1, L2E, tjL), 0.f);                             \
          float p  = fexp2(a_) * iD;                                             \
          const int prow = ih*32 + t2*16 + g*4 + r;                              \
          *(short*)(Pb + prow*128 + (((jl>>3) ^ (prow&7))<<4) + (jl&7)*2) = f2bf(p); \
        }                                                                        \
      }                                                                          \
    }                                                                            \
    if ((K) < 63) {                                                              \
      *(short8*)((char*)ejlds[((K)+1)&1] + sbyte) = stg;                         \
      const int k2n = (K) < 62 ? (K) + 2 : 63;                                   \
      stg = *(const short8*)(emb + (bbase + (size_t)k2n*64 + srow)*FC + sc8*8);  \
    }                                                                            \
    __syncthreads();                                                             \
    {                                                                            \
      const char* Pb = (const char*)Plds[(K)&1];                                 \
      _Pragma("unroll")                                                          \
      for (int m = 0; m < 4; ++m) {                                              \
        const int prow = m*16 + n16;                                             \
        short8 pa0 = *(const short8*)(Pb + prow*128 + (((0*4+g)<<4) ^ ((prow&7)<<4))); \
        short8 pa1 = *(const short8*)(Pb + prow*128 + (((1*4+g)<<4) ^ ((prow&7)<<4))); \
        acc[m][0] = __builtin_amdgcn_mfma_f32_16x16x32_bf16(pa0, bfC[0], acc[m][0], 0,0,0); \
        acc[m][0] = __builtin_amdgcn_mfma_f32_16x16x32_bf16(pa1, bfC[1], acc[m][0], 0,0,0); \
        acc[m][1] = __builtin_amdgcn_mfma_f32_16x16x32_bf16(pa0, bfC[2], acc[m][1], 0,0,0); \
        acc[m][1] = __builtin_amdgcn_mfma_f32_16x16x32_bf16(pa1, bfC[3], acc[m][1], 0,0,0); \
      }                                                                          \
    }                                                                            \
  }

__global__ __launch_bounds__(512) void k_attn(const float* __restrict__ fm,
    const short* __restrict__ emb, const float* __restrict__ sqn,
    const float* __restrict__ T, const float* __restrict__ D,
    const short* __restrict__ sct2, float* __restrict__ out)
{
    const int bid = ((blockIdx.x & 7) << 5) | (blockIdx.x >> 3);  // 256 blocks
    const int b = bid >> 6;
    const int i0 = (bid & 63) * 64;
    const int t = threadIdx.x, w = t >> 6, lane = t & 63, g = lane >> 4, n16 = lane & 15;
    const size_t bbase = (size_t)b * HW;
    const size_t ibase = bbase + i0;
    __shared__ short ejlds[2][64*64];
    __shared__ short Plds[2][64*64];

    const int ih = w & 1, jq = w >> 1;
    const int jl = jq * 16 + n16;
    short8 aQ0[2], aQ1[2];
    float snL[2][4];
    #pragma unroll
    for (int t2 = 0; t2 < 2; ++t2) {
        const size_t qr = ibase + ih*32 + t2*16 + n16;
        aQ0[t2] = *(const short8*)(emb + qr*FC + g*8);
        aQ1[t2] = *(const short8*)(emb + qr*FC + 32 + g*8);
        #pragma unroll
        for (int r = 0; r < 4; ++r)
            snL[t2][r] = -L2E * sqn[ibase + ih*32 + t2*16 + g*4 + r];
    }
    const int srow = t >> 3, sc8 = t & 7;
    const int sbyte = srow*128 + ((sc8*16) ^ ((srow&7)<<4));
    short8 stg = *(const short8*)(emb + (bbase + srow)*FC + sc8*8);
    *(short8*)((char*)ejlds[0] + sbyte) = stg;
    stg = *(const short8*)(emb + (bbase + 64 + srow)*FC + sc8*8);
    float sqA = sqn[bbase + jl], tA = T[bbase + jl], dA = D[bbase + jl];
    float sqB, tB, dB;
    short8 bfA[4], bfB[4];
    {
        const short* sb0 = sct2 + ((size_t)(b*64)*8)*2048 + (size_t)(w*32 + n16)*8;
        #pragma unroll
        for (int nn = 0; nn < 2; ++nn)
            #pragma unroll
            for (int kc = 0; kc < 2; ++kc)
                bfA[nn*2+kc] = *(const short8*)(sb0 + (size_t)(kc*4+g)*2048 + nn*128);
    }
    f32x4 acc[4][2];
    #pragma unroll
    for (int m = 0; m < 4; ++m) { acc[m][0] = (f32x4){0.f,0.f,0.f,0.f}; acc[m][1] = (f32x4){0.f,0.f,0.f,0.f}; }
    __syncthreads();

    for (int k2 = 0; k2 < 64; k2 += 2) {
        ATTN_ITER(k2,   bfA, sqA, tA, dA, bfB, sqB, tB, dB);
        ATTN_ITER(k2+1, bfB, sqB, tB, dB, bfA, sqA, tA, dA);
    }

    #pragma unroll
    for (int m = 0; m < 4; ++m)
        #pragma unroll
        for (int r = 0; r < 4; ++r) {
            const size_t row = ibase + m*16 + g*4 + r;
            #pragma unroll
            for (int nn = 0; nn < 2; ++nn) {
                const size_t idx = row*CC + w*32 + nn*16 + n16;
                out[idx] = fm[idx] + acc[m][nn][r];
            }
        }
}

extern "C" void kernel_launch(void* const* d_in, const int* in_sizes, int n_in,
                              void* d_out, int out_size, void* d_ws, size_t ws_size,
                              hipStream_t stream)
{
    const float* fm   = (const float*)d_in[0];
    const float* Wemb = (const float*)d_in[1];
    const float* bemb = (const float*)d_in[2];
    const float* Watt = (const float*)d_in[3];
    const float* batt = (const float*)d_in[4];
    const float* Wthr = (const float*)d_in[5];
    const float* bthr = (const float*)d_in[6];
    char* ws = (char*)d_ws;
    short* emb   = (short*)(ws + OFF_EMB);
    short* sct2  = (short*)(ws + OFF_SCT2);
    float* sqn   = (float*)(ws + OFF_SQN);
    float* T     = (float*)(ws + OFF_T);
    float* D     = (float*)(ws + OFF_D);
    short* Wemb2 = (short*)(ws + OFF_WEMB2);
    short* Watt2 = (short*)(ws + OFF_WATT2);
    float* out = (float*)d_out;

    k_prep  <<<320,  256, 0, stream>>>(Wemb, Watt, Wemb2, Watt2, D);
    k_front <<<1024, 256, 0, stream>>>(fm, Wemb2, Watt2, bemb, batt, Wthr, bthr,
                                       emb, sct2, sqn, T);
    k_colsum<<<2048, 256, 0, stream>>>(emb, sqn, T, D);
    k_attn  <<<256,  512, 0, stream>>>(fm, emb, sqn, T, D, sct2, out);
}